// Round 3
// baseline (693.777 us; speedup 1.0000x reference)
//
#include <hip/hip_runtime.h>

// Correlation: out[b, di*9+dj, h, w] = (1/64) * sum_c x1[b,c,h,w] * x2p[b,c,h+di,w+dj]
// x2p = zero-pad-4. B=8, C=64, H=W=192.
//
// Round-3 design (round-2 failed on acc spills + 9-wave-block occupancy cliff):
//  - Block = 512 thr (8 waves). wave = pixel row r; lane = di*7 + xg
//    (di in [0,9), xg in [0,7) -> 4 consecutive w-pixels; lane 63 masked).
//    Tile 28x8 pixels. acc[9 dj][4 px] = 36 VGPRs; V budget 128 via
//    __launch_bounds__(512,4) -> 2 blocks/CU guaranteed (16 waves, 50% occ),
//    no spill pressure.
//  - LDS holds ONLY the x2 halo (36x16 floats x CK=8 ch = 18 KB), ping-pong
//    36 KB total. x1 comes straight from global: one float4 per channel per
//    thread, 9 lanes share each float4 -> L1 broadcast.
//  - Staging via global_load_lds width=16; OOB float4s (pad=4 == float4) read
//    a zero __device__ page. LDS dst is linear idx*16 -> wave-uniform base +
//    lane*16 as required.
//  - Order per chunk: barrier -> compute k (ds_reads first in program order,
//    no vmcnt stall) -> issue DMA for k+1 -> barrier (drain overlapped by the
//    co-resident block's compute).
//  - XCD swizzle: blockIdx%8 = batch -> each XCD streams one image (halo
//    reuse in its private L2).

constexpr int MAXD = 4, OD = 9, ND = 81;
constexpr int GX = 7;                 // float4 col-groups per tile
constexpr int TW = 28, TH = 8;        // tile pixels
constexpr int CK = 8;                 // channels per chunk
constexpr int HLW = TW + 2 * MAXD;    // 36 floats
constexpr int HLH = TH + 2 * MAXD;    // 16 rows
constexpr int NT  = 512;
constexpr int Bc = 8, Cc = 64, Hc = 192, Wc = 192, HW = Hc * Wc;
constexpr int NCH = Cc / CK;          // 8 chunks
constexpr int Q_PER_CH = HLH * (HLW / 4);   // 144 float4 per channel
constexpr int X2Q = CK * Q_PER_CH;          // 1152 float4 per chunk
constexpr int TILES_W = 7, TILES_H = 24;    // 7*28=196 >= 192

__device__ __attribute__((aligned(16))) float g_zero_page[4];  // bss, stays 0

__device__ __forceinline__ void async_cp16(const float* src, float* lds_dst) {
    __builtin_amdgcn_global_load_lds(
        (const __attribute__((address_space(1))) unsigned int*)src,
        (__attribute__((address_space(3))) unsigned int*)lds_dst,
        16, 0, 0);
}

__global__ __launch_bounds__(NT, 4) void corr_kernel(
    const float* __restrict__ x1, const float* __restrict__ x2,
    float* __restrict__ out)
{
    __shared__ float sx2[2][CK * HLH * HLW];   // 2 x 18 KB

    const int tid  = threadIdx.x;
    const int lane = tid & 63;
    const int r    = tid >> 6;            // wave id = row in tile, 0..7
    int di = lane / 7;                    // 0..9 (lane 63 -> 9)
    const int xg = lane - di * 7;         // 0..6
    const bool active = (di < OD);
    if (di > 8) di = 8;                   // clamp; lane 63 computes garbage, no store

    // ---- tile decode with XCD swizzle: lin%8 = batch ----
    const int lin = blockIdx.x;
    const int b   = lin & 7;
    const int t   = lin >> 3;             // 0..167
    const int th_ = t / TILES_W;
    const int tw_ = t - th_ * TILES_W;
    const int w0  = tw_ * TW;
    const int h0  = th_ * TH;

    const float* x1b = x1 + (long)b * Cc * HW;
    const float* x2b = x2 + (long)b * Cc * HW;

    const int  myw    = w0 + xg * 4;                 // multiple of 4
    const bool colok  = (myw < Wc);                  // float4 fully in-bounds
    const bool storeok = active && colok;

    // ---- stage one chunk of x2 halo into buffer buf ----
    auto stage_one = [&](int c0, int buf, int idx) {  // idx in [0, X2Q)
        int c   = idx / Q_PER_CH;
        int rem = idx - c * Q_PER_CH;
        int y   = rem / (HLW / 4);
        int xq  = rem - y * (HLW / 4);
        int gy  = h0 + y - MAXD;
        int gx  = w0 + xq * 4 - MAXD;                // multiple of 4
        const float* src =
            ((unsigned)gy < (unsigned)Hc && (unsigned)gx < (unsigned)Wc)
                ? (x2b + (long)(c0 + c) * HW + gy * Wc + gx)
                : g_zero_page;
        async_cp16(src, &sx2[buf][idx * 4]);
    };
    auto stage = [&](int c0, int buf) {
        stage_one(c0, buf, tid);
        stage_one(c0, buf, tid + NT);
        if (tid < X2Q - 2 * NT)                      // waves 0,1 fully active
            stage_one(c0, buf, tid + 2 * NT);
    };

    float acc[OD][4];
#pragma unroll
    for (int dj = 0; dj < OD; ++dj)
#pragma unroll
        for (int p = 0; p < 4; ++p) acc[dj][p] = 0.f;

    // x1 source for this thread (per channel): coalesced float4, L1-broadcast
    const float* x1p = colok ? (x1b + (h0 + r) * Wc + myw) : g_zero_page;
    const long  x1stride = colok ? (long)HW : 0;

    stage(0, 0);

    for (int k = 0; k < NCH; ++k) {
        const int cur = k & 1;
        __syncthreads();   // drains this block's DMA for chunk k

        // ---- compute chunk k ----
#pragma unroll
        for (int c = 0; c < CK; ++c) {
            float4 a = *(const float4*)(x1p + (long)(k * CK + c) * x1stride);
            const float* wr = &sx2[cur][(c * HLH + r + di) * HLW + xg * 4];
            float4 b0 = *(const float4*)(wr);
            float4 b1 = *(const float4*)(wr + 4);
            float4 b2 = *(const float4*)(wr + 8);
            float win[12] = {b0.x, b0.y, b0.z, b0.w,
                             b1.x, b1.y, b1.z, b1.w,
                             b2.x, b2.y, b2.z, b2.w};
            float av[4] = {a.x, a.y, a.z, a.w};
#pragma unroll
            for (int dj = 0; dj < OD; ++dj)
#pragma unroll
                for (int p = 0; p < 4; ++p)
                    acc[dj][p] = fmaf(av[p], win[dj + p], acc[dj][p]);
        }

        // ---- issue DMA for chunk k+1 (after compute's ds_reads in program order)
        if (k + 1 < NCH)
            stage((k + 1) * CK, cur ^ 1);
    }

    // ---- epilogue ----
    if (storeok) {
        const float scale = 1.0f / 64.0f;
        float* ob = out + (((long)b * ND + di * OD) * Hc + (h0 + r)) * Wc + myw;
#pragma unroll
        for (int dj = 0; dj < OD; ++dj) {
            float4 o;
            o.x = acc[dj][0] * scale;
            o.y = acc[dj][1] * scale;
            o.z = acc[dj][2] * scale;
            o.w = acc[dj][3] * scale;
            *(float4*)(ob + (long)dj * HW) = o;
        }
    }
}

extern "C" void kernel_launch(void* const* d_in, const int* in_sizes, int n_in,
                              void* d_out, int out_size, void* d_ws, size_t ws_size,
                              hipStream_t stream) {
    const float* x1 = (const float*)d_in[0];
    const float* x2 = (const float*)d_in[1];
    float* out = (float*)d_out;
    const int nblocks = Bc * TILES_W * TILES_H;   // 1344
    corr_kernel<<<dim3(nblocks), dim3(NT), 0, stream>>>(x1, x2, out);
}